// Round 1
// baseline (904.151 us; speedup 1.0000x reference)
//
#include <hip/hip_runtime.h>

// CCLayer: ZPi (288 x 262144) f32, U (256 x 32) f32, alpha (32) f32.
// Z = ZPi[:256], Pi = ZPi[256:].
// out[:256] = Z * sum_pi + U @ ((alpha - U^T Z) * Pi);  out[256:] = Pi.
//
// Strategy: single fused pass. Block = 512 threads (8 waves), tile = 64 cols.
// Wave q handles rows q*32..q*32+31; lane = column. z kept in 32 VGPRs per
// thread (no Z re-read from HBM). utz partial-reduced across waves via LDS.
// U / alpha accessed with wave-uniform indices -> scalar loads, so the two
// 32x32-FMA loops are pure v_fma with SGPR operand (no per-FMA mem traffic).

#define NCOLS 262144
#define DROWS 256
#define PROWS 32

__global__ __launch_bounds__(512, 4) void CCLayer_kernel(
    const float* __restrict__ ZPi,
    const float* __restrict__ U,
    const float* __restrict__ alpha,
    float* __restrict__ out)
{
    __shared__ float utz_part[8][PROWS][64];  // 64 KB
    __shared__ float sp[8][64];               //  2 KB
    __shared__ float w_lds[PROWS][64];        //  8 KB

    const int col = threadIdx.x & 63;
    const int q   = __builtin_amdgcn_readfirstlane((int)(threadIdx.x >> 6)); // wave id, scalar
    const int n   = blockIdx.x * 64 + col;

    // ---- Pi: each thread loads 4 rows (p = q*4+j), copies to out, partial sum ----
    float pi[4];
    float psum = 0.f;
    #pragma unroll
    for (int j = 0; j < 4; ++j) {
        const int p = q * 4 + j;
        const size_t idx = (size_t)(DROWS + p) * NCOLS + n;
        const float v = ZPi[idx];
        pi[j] = v;
        out[idx] = v;
        psum += v;
    }
    sp[q][col] = psum;

    // ---- Z: load this wave's 32 rows into registers ----
    float z[32];
    const float* zbase = ZPi + (size_t)(q * 32) * NCOLS + n;
    #pragma unroll
    for (int d = 0; d < 32; ++d)
        z[d] = zbase[(size_t)d * NCOLS];

    // ---- partial utz[p] = sum_{d in this wave's rows} U[d][p] * z[d] ----
    float utz[PROWS];
    #pragma unroll
    for (int p = 0; p < PROWS; ++p) utz[p] = 0.f;

    #pragma unroll
    for (int d = 0; d < 32; ++d) {
        const float* urow = U + (size_t)(q * 32 + d) * PROWS;  // uniform -> s_load
        #pragma unroll
        for (int p = 0; p < PROWS; ++p)
            utz[p] += urow[p] * z[d];
    }
    #pragma unroll
    for (int p = 0; p < PROWS; ++p)
        utz_part[q][p][col] = utz[p];

    __syncthreads();

    // ---- reduce over waves for this thread's 4 p's; w = (alpha - utz)*pi ----
    #pragma unroll
    for (int j = 0; j < 4; ++j) {
        const int p = q * 4 + j;
        float t = 0.f;
        #pragma unroll
        for (int qq = 0; qq < 8; ++qq)
            t += utz_part[qq][p][col];
        w_lds[p][col] = (alpha[p] - t) * pi[j];
    }
    __syncthreads();

    // ---- s (column pi-sum) and w into registers ----
    float s = 0.f;
    #pragma unroll
    for (int qq = 0; qq < 8; ++qq)
        s += sp[qq][col];

    float w[PROWS];
    #pragma unroll
    for (int p = 0; p < PROWS; ++p)
        w[p] = w_lds[p][col];

    // ---- out rows: acc = s*z[d] + sum_p U[d][p]*w[p] ----
    float* obase = out + (size_t)(q * 32) * NCOLS + n;
    #pragma unroll
    for (int d = 0; d < 32; ++d) {
        const float* urow = U + (size_t)(q * 32 + d) * PROWS;  // uniform -> s_load
        float acc = s * z[d];
        #pragma unroll
        for (int p = 0; p < PROWS; ++p)
            acc += urow[p] * w[p];
        obase[(size_t)d * NCOLS] = acc;
    }
}

extern "C" void kernel_launch(void* const* d_in, const int* in_sizes, int n_in,
                              void* d_out, int out_size, void* d_ws, size_t ws_size,
                              hipStream_t stream) {
    const float* ZPi   = (const float*)d_in[0];
    const float* U     = (const float*)d_in[1];
    const float* alpha = (const float*)d_in[2];
    float* out = (float*)d_out;

    dim3 grid(NCOLS / 64);   // 4096 blocks
    dim3 block(512);         // 8 waves
    CCLayer_kernel<<<grid, block, 0, stream>>>(ZPi, U, alpha, out);
}